// Round 6
// baseline (96.155 us; speedup 1.0000x reference)
//
#include <hip/hip_runtime.h>
#include <hip/hip_bf16.h>

#define D_S 128

typedef short bf16x8 __attribute__((ext_vector_type(8)));
typedef float f32x4 __attribute__((ext_vector_type(4)));

__device__ __forceinline__ unsigned short f32_to_bf16(float f) {
  unsigned int u = __float_as_uint(f);
  return (unsigned short)((u + 0x7FFFu + ((u >> 16) & 1u)) >> 16);  // RN-even
}
__device__ __forceinline__ unsigned int pack2_bf16(float lo, float hi) {
  return (unsigned int)f32_to_bf16(lo) | ((unsigned int)f32_to_bf16(hi) << 16);
}
__device__ __forceinline__ bf16x8 cvt_frag(float4 x, float4 y) {
  union { bf16x8 v; unsigned int u[4]; } r;
  r.u[0] = pack2_bf16(x.x, x.y);
  r.u[1] = pack2_bf16(x.z, x.w);
  r.u[2] = pack2_bf16(y.x, y.y);
  r.u[3] = pack2_bf16(y.z, y.w);
  return r.v;
}

// ---------------------------------------------------------------------------
// Kernel 0: W1 (fp32, torch layout [128][256]) -> W1bf (bf16, concat-row
// layout [256][128]): row j<128 = W1[j][0:128], row j>=128 = W1[j-128][128:256].
// Removes the per-block f32->bf16 pack work (256 VALU/wave) and halves the
// ~205 MB of L2 W1 re-reads that every precompute block did in R5.
// ---------------------------------------------------------------------------
__global__ __launch_bounds__(256) void w1_to_bf16(
    const float* __restrict__ W1, unsigned short* __restrict__ W1bf) {
  int idx4 = (blockIdx.x * 256 + threadIdx.x) * 4;  // 65536 elements total
  int j = idx4 >> 7, k = idx4 & 127;
  const float* src =
      W1 + ((j < D_S) ? (size_t)j * (2 * D_S) + k : (size_t)(j - D_S) * (2 * D_S) + D_S + k);
  float4 v = *(const float4*)src;
  ushort4 o = make_ushort4(f32_to_bf16(v.x), f32_to_bf16(v.y),
                           f32_to_bf16(v.z), f32_to_bf16(v.w));
  *(ushort4*)(W1bf + idx4) = o;
}

// ---------------------------------------------------------------------------
// Kernel 1 (MFMA): AB[n][j] = Wc[j] . s[n] (+ b1[j] for j<128), bf16 out.
// Grid (ceil(n/64), 2): block = 64-node x 128-j tile (chunk = blockIdx.y).
// R5 -> R6: one chunk per block (halved serial path, 2x blocks) and B
// fragments are direct bf16x8 loads from W1bf (no per-block cvt).
// D layout (m89-verified): col = lane&15, row = (lane>>4)*4 + reg.
// Output bounced via o_tile so global stores are 16B-contiguous per row.
// ---------------------------------------------------------------------------
__global__ __launch_bounds__(256) void precompute_mfma(
    const float* __restrict__ s, const unsigned short* __restrict__ W1bf,
    const float* __restrict__ b1, unsigned short* __restrict__ AB,
    int n_nodes) {
  __shared__ __align__(16) unsigned short o_tile[64][136];  // 17.4 KB
  int t = threadIdx.x;
  int wv = t >> 6, lane = t & 63;
  int lr = lane & 15, lc = lane >> 4;
  int n0 = blockIdx.x * 64;
  int chunk = blockIdx.y;

  // B fragments first (L2-hot 64KB table): 2 n-tiles x 4 k-steps.
  bf16x8 bfr[2][4];
  {
    const unsigned short* wb =
        W1bf + (size_t)(chunk * 128 + wv * 32 + lr) * D_S + lc * 8;
#pragma unroll
    for (int nt = 0; nt < 2; ++nt)
#pragma unroll
      for (int ks = 0; ks < 4; ++ks)
        bfr[nt][ks] = *(const bf16x8*)(wb + nt * 16 * D_S + ks * 32);
  }

  // A fragments: 4 m-tiles x 4 k-steps, f32 global + in-reg RNE cvt.
  bf16x8 afrag[4][4];
#pragma unroll
  for (int m = 0; m < 4; ++m) {
    int r = n0 + m * 16 + lr;
    if (r > n_nodes - 1) r = n_nodes - 1;  // clamp; junk rows masked at store
    const float* ap = s + (size_t)r * D_S + lc * 8;
#pragma unroll
    for (int ks = 0; ks < 4; ++ks) {
      float4 x = *(const float4*)(ap + ks * 32);
      float4 y = *(const float4*)(ap + ks * 32 + 4);
      afrag[m][ks] = cvt_frag(x, y);
    }
  }

  f32x4 acc[4][2] = {};
#pragma unroll
  for (int ks = 0; ks < 4; ++ks)
#pragma unroll
    for (int m = 0; m < 4; ++m)
#pragma unroll
      for (int nt = 0; nt < 2; ++nt)
        acc[m][nt] = __builtin_amdgcn_mfma_f32_16x16x32_bf16(
            afrag[m][ks], bfr[nt][ks], acc[m][nt], 0, 0, 0);

  if (chunk == 0) {  // bias folds into the A-half only
#pragma unroll
    for (int nt = 0; nt < 2; ++nt) {
      float bv = b1[wv * 32 + nt * 16 + lr];
#pragma unroll
      for (int m = 0; m < 4; ++m)
#pragma unroll
        for (int r = 0; r < 4; ++r) acc[m][nt][r] += bv;
    }
  }

  // D -> LDS (bf16), then coalesced copy-out.
#pragma unroll
  for (int m = 0; m < 4; ++m)
#pragma unroll
    for (int nt = 0; nt < 2; ++nt) {
      int colc = wv * 32 + nt * 16 + lr;
#pragma unroll
      for (int r = 0; r < 4; ++r)
        o_tile[m * 16 + lc * 4 + r][colc] = f32_to_bf16(acc[m][nt][r]);
    }
  __syncthreads();
#pragma unroll
  for (int rep = 0; rep < 4; ++rep) {
    int idx = t + rep * 256;        // 1024 chunks of 8 bf16 (64 rows x 16)
    int rowi = idx >> 4, cg = (idx & 15) * 8;
    int gn = n0 + rowi;
    if (gn < n_nodes) {
      uint4 v = *(const uint4*)&o_tile[rowi][cg];
      *(uint4*)(AB + (size_t)gn * 256 + chunk * D_S + cg) = v;
    }
  }
}

// ---------------------------------------------------------------------------
// Kernel 2: per-edge. 16 edges/wave: 8 groups x 8 lanes, 2 edges per group.
//   out[e] = sum_k W2[k] * silu(A[row][k] + B[col][k]) + b2
// Per lane: 8 independent dwordx4 gathers in flight (R5 had 4) -> 2x
// memory-level parallelism for the latency-bound middle regime (R5: VALU 65%,
// HBM 42%, neither saturated). W2 regs + indices (int2) amortized over the
// edge pair; float2 output store.
// ---------------------------------------------------------------------------
__device__ __forceinline__ float silu2(unsigned int ua, unsigned int ub,
                                       float wlo, float whi) {
  float h0 = __uint_as_float(ua << 16) + __uint_as_float(ub << 16);
  float h1 = __uint_as_float(ua & 0xFFFF0000u) + __uint_as_float(ub & 0xFFFF0000u);
  float e0 = __builtin_amdgcn_exp2f(h0 * -1.442695041f);
  float e1 = __builtin_amdgcn_exp2f(h1 * -1.442695041f);
  float r0 = __builtin_amdgcn_rcpf(1.f + e0);
  float r1 = __builtin_amdgcn_rcpf(1.f + e1);
  return h0 * r0 * wlo + h1 * r1 * whi;
}

__device__ __forceinline__ float silu_dot16(uint4 a0, uint4 a1, uint4 b0,
                                            uint4 b1v, float4 w0, float4 w1,
                                            float4 w2, float4 w3) {
  float p = 0.f;
  p += silu2(a0.x, b0.x, w0.x, w0.y);
  p += silu2(a0.y, b0.y, w0.z, w0.w);
  p += silu2(a0.z, b0.z, w1.x, w1.y);
  p += silu2(a0.w, b0.w, w1.z, w1.w);
  p += silu2(a1.x, b1v.x, w2.x, w2.y);
  p += silu2(a1.y, b1v.y, w2.z, w2.w);
  p += silu2(a1.z, b1v.z, w3.x, w3.y);
  p += silu2(a1.w, b1v.w, w3.z, w3.w);
  return p;
}

__global__ __launch_bounds__(256) void edge_kernel(
    const int* __restrict__ ei, const unsigned short* __restrict__ AB,
    const float* __restrict__ W2, const float* __restrict__ b2,
    float* __restrict__ out, int E) {
  int t = threadIdx.x;
  int wv = (blockIdx.x << 2) + (t >> 6);
  int lane = t & 63;
  int g = lane >> 3, sub = lane & 7;
  int e0 = wv * 16 + (g << 1);
  if (e0 > E - 2) e0 = E - 2;  // clamped waves recompute same values: benign

  int2 rr = *(const int2*)(ei + e0);      // rows of edge pair
  int2 cc = *(const int2*)(ei + E + e0);  // cols of edge pair

  unsigned int sh = (unsigned int)(sub << 4);
  unsigned int offA0 = ((unsigned int)rr.x << 8) + sh;
  unsigned int offA1 = ((unsigned int)rr.y << 8) + sh;
  unsigned int offB0 = ((unsigned int)cc.x << 8) + 128 + sh;
  unsigned int offB1 = ((unsigned int)cc.y << 8) + 128 + sh;

  uint4 a00 = *(const uint4*)(AB + offA0);
  uint4 a01 = *(const uint4*)(AB + offA0 + 8);
  uint4 b00 = *(const uint4*)(AB + offB0);
  uint4 b01 = *(const uint4*)(AB + offB0 + 8);
  uint4 a10 = *(const uint4*)(AB + offA1);
  uint4 a11 = *(const uint4*)(AB + offA1 + 8);
  uint4 b10 = *(const uint4*)(AB + offB1);
  uint4 b11 = *(const uint4*)(AB + offB1 + 8);

  const float4* wp = (const float4*)(W2 + (sub << 4));
  float4 w0 = wp[0], w1 = wp[1], w2 = wp[2], w3 = wp[3];

  float p0 = silu_dot16(a00, a01, b00, b01, w0, w1, w2, w3);
  float p1 = silu_dot16(a10, a11, b10, b11, w0, w1, w2, w3);

#pragma unroll
  for (int off = 1; off < 8; off <<= 1) {
    p0 += __shfl_xor(p0, off, 64);
    p1 += __shfl_xor(p1, off, 64);
  }

  if (sub == 0) {
    float bb = b2[0];
    *(float2*)(out + e0) = make_float2(p0 + bb, p1 + bb);
  }
}

// ---------------------------------------------------------------------------
// Fallback (workspace too small): direct per-edge compute, fp32.
// ---------------------------------------------------------------------------
__global__ __launch_bounds__(256) void edge_direct(
    const float* __restrict__ s, const int* __restrict__ ei,
    const float* __restrict__ W1, const float* __restrict__ b1,
    const float* __restrict__ W2, const float* __restrict__ b2,
    float* __restrict__ out, int E) {
  __shared__ float sh[256];
  __shared__ float red[128];
  int e = blockIdx.x;
  int t = threadIdx.x;
  int row = ei[e], col = ei[E + e];
  sh[t] = (t < 128) ? s[(size_t)row * D_S + t] : s[(size_t)col * D_S + (t - 128)];
  __syncthreads();
  if (t < 128) {
    float acc = b1[t];
    const float* w = W1 + (size_t)t * 256;
#pragma unroll 8
    for (int jj = 0; jj < 256; ++jj) acc += sh[jj] * w[jj];
    red[t] = (acc / (1.f + __expf(-acc))) * W2[t];
  }
  __syncthreads();
  if (t < 64) {
    float x = red[t] + red[t + 64];
#pragma unroll
    for (int off = 32; off; off >>= 1) x += __shfl_xor(x, off, 64);
    if (t == 0) out[e] = x + b2[0];
  }
}

extern "C" void kernel_launch(void* const* d_in, const int* in_sizes, int n_in,
                              void* d_out, int out_size, void* d_ws, size_t ws_size,
                              hipStream_t stream) {
  const float* s  = (const float*)d_in[0];
  const int*   ei = (const int*)d_in[1];
  const float* W1 = (const float*)d_in[2];
  const float* b1 = (const float*)d_in[3];
  const float* W2 = (const float*)d_in[4];
  const float* b2 = (const float*)d_in[5];
  float* out = (float*)d_out;

  int n_nodes = in_sizes[0] / D_S;
  int E = in_sizes[1] / 2;

  size_t ab_elems = (size_t)n_nodes * 256;
  size_t need = (ab_elems + 65536) * sizeof(unsigned short);
  if (ws_size >= need && E >= 2) {
    unsigned short* AB = (unsigned short*)d_ws;
    unsigned short* W1bf = AB + ab_elems;
    w1_to_bf16<<<64, 256, 0, stream>>>(W1, W1bf);
    dim3 g1((n_nodes + 63) / 64, 2);
    precompute_mfma<<<g1, 256, 0, stream>>>(s, W1bf, b1, AB, n_nodes);
    int blocks = (E + 63) / 64;  // 4 waves/block, 16 edges/wave
    edge_kernel<<<blocks, 256, 0, stream>>>(ei, AB, W2, b2, out, E);
  } else {
    edge_direct<<<E, 256, 0, stream>>>(s, ei, W1, b1, W2, b2, out, E);
  }
}